// Round 4
// baseline (1245.273 us; speedup 1.0000x reference)
//
#include <hip/hip_runtime.h>

#define NB 128
#define TT 512
#define TAG 256
#define START (TAG - 2)
#define STOP (TAG - 1)
#define MARGIN 0.03125f   // >> max fp32 rounding slack (~4e-4 at |part|~1500)

// One block per batch element, 256 threads (thread tid owns output tag j=tid).
// Exact candidate pruning: rows i with part[i] < pmax - (Tmax-Tmin) - MARGIN
// cannot win ANY column (value or first-occurrence argmax): their cur is
// >= MARGIN below the pmax-holder's cur for every j, and MARGIN dwarfs fp32
// rounding. Surviving arithmetic replicates the reference bit-exactly:
// (emit + T) + part, strict > over ascending i.
// 2 barriers/step: per-wave candidate segments need no cross-wave prefix.
__global__ __launch_bounds__(256) void viterbi_pruned(
    const float* __restrict__ feats,   // [NB][TT][TAG] f32
    const int*   __restrict__ mask,    // [NB][TT] i32
    const float* __restrict__ trans,   // [TAG][TAG] f32
    float* __restrict__ out)           // [NB] scores ++ [NB][TT] decode (as f32)
{
    __shared__ float plast[TAG];          // partition at t = len-1
    __shared__ float pcand[TAG];          // candidate part values (per-wave segs)
    __shared__ int   cand[TAG];           // candidate row indices (per-wave segs)
    __shared__ int   ncs[4];              // per-wave candidate counts
    __shared__ __align__(16) float wavemax[4];
    __shared__ __align__(16) float redmx[4];
    __shared__ __align__(16) float redmn[4];
    __shared__ unsigned char bp[TT][TAG]; // backpointers, 128 KiB
    __shared__ float fvals[TAG];
    __shared__ int s_len;

    const int b    = blockIdx.x;
    const int tid  = threadIdx.x;
    const int w    = tid >> 6;
    const int lane = tid & 63;

    const float* fb = feats + (size_t)b * TT * TAG;
    const int*   mb = mask  + (size_t)b * TT;

    // ---- lengths[b] = sum(mask) ----
    if (tid == 0) s_len = 0;
    __syncthreads();
    {
        int lm = mb[tid] + mb[tid + 256];
        for (int o = 32; o; o >>= 1) lm += __shfl_xor(lm, o);
        if (lane == 0) atomicAdd(&s_len, lm);
    }

    // ---- global Tmax/Tmin over trans (once) ----
    float tmx = -INFINITY, tmn = INFINITY;
    for (int k = tid; k < TAG * TAG / 4; k += 256) {
        float4 v = ((const float4*)trans)[k];
        tmx = fmaxf(tmx, fmaxf(fmaxf(v.x, v.y), fmaxf(v.z, v.w)));
        tmn = fminf(tmn, fminf(fminf(v.x, v.y), fminf(v.z, v.w)));
    }
    for (int o = 32; o; o >>= 1) {
        tmx = fmaxf(tmx, __shfl_xor(tmx, o));
        tmn = fminf(tmn, __shfl_xor(tmn, o));
    }
    if (lane == 0) { redmx[w] = tmx; redmn[w] = tmn; }
    __syncthreads();
    float4 rx = *(const float4*)redmx;
    float4 rn = *(const float4*)redmn;
    const float Wwin = (fmaxf(fmaxf(rx.x, rx.y), fmaxf(rx.z, rx.w))
                      - fminf(fminf(rn.x, rn.y), fminf(rn.z, rn.w))) + MARGIN;
    const int len = s_len;
    const int lastidx = (len > 0) ? (len - 1) : 0;

    // ---- t = 0: part0 = feats[b,0,:] + trans[START,:] ----
    float m = fb[tid] + trans[START * TAG + tid];  // this thread's part[j=tid]
    if (lastidx == 0) plast[tid] = m;

    // emit prefetch, one full iteration ahead (feats are cold HBM reads)
    float emitN = fb[(size_t)TAG + tid];           // emit for t=1

    // ---- forward scan t = 1..TT-1 ----
    for (int t = 1; t < TT; ++t) {
        const float emit = emitN;
        const int   tn   = (t + 1 < TT) ? t + 1 : t;
        emitN = fb[(size_t)tn * TAG + tid];        // in flight ~1 full step
        const int mk = mb[t];

        // publish per-wave max of part
        float wm = m;
        for (int o = 32; o; o >>= 1) wm = fmaxf(wm, __shfl_xor(wm, o));
        if (lane == 0) wavemax[w] = wm;
        __syncthreads();                           // BAR_A: wavemax visible

        // threshold + per-wave compaction (ascending i preserved via segments)
        float4 wv = *(const float4*)wavemax;
        const float pmax = fmaxf(fmaxf(wv.x, wv.y), fmaxf(wv.z, wv.w));
        const float thr  = pmax - Wwin;
        const bool flag  = (m >= thr);
        unsigned long long bal = __ballot(flag);
        if (flag) {
            int rank = __popcll(bal & ((1ull << lane) - 1ull));
            cand[(w << 6) + rank]  = tid;
            pcand[(w << 6) + rank] = m;
        }
        if (lane == 0) ncs[w] = __popcll(bal);
        __syncthreads();                           // BAR_B: cand/pcand/ncs ready

        // reduce over candidates, segments in ascending order -> global
        // ascending i -> strict > == first-occurrence argmax (as reference)
        float nm = -INFINITY;
        int bidx = 0;
        #pragma unroll
        for (int seg = 0; seg < 4; ++seg) {
            const int n = __builtin_amdgcn_readfirstlane(ncs[seg]);
            for (int r = 0; r < n; r += 8) {
                #pragma unroll
                for (int c = 0; c < 8; ++c) {
                    const int rr = r + c;
                    if (rr < n) {                  // scalar (uniform) guard
                        const int   ic  = cand[(seg << 6) + rr];
                        const float pv  = pcand[(seg << 6) + rr];
                        const float tv  = trans[ic * TAG + tid];
                        const float cur = (emit + tv) + pv;  // exact association
                        if (cur > nm) { nm = cur; bidx = ic; }
                    }
                }
            }
        }

        bp[t][tid] = (unsigned char)((mk > 0) ? bidx : 0);
        m = nm;
        if (t == lastidx) plast[tid] = m;
    }

    // ---- stop transition: column STOP only ----
    fvals[tid] = plast[tid] + trans[(size_t)tid * TAG + STOP];
    __syncthreads();

    if (tid == 0) {
        float mm = -INFINITY; int p = 0;
        for (int i = 0; i < TAG; ++i) {
            float v = fvals[i];
            if (v > mm) { mm = v; p = i; }
        }
        out[b] = mm;                      // path_score
        // ---- backtrack (LDS pointer chase) ----
        float* dec = out + NB + (size_t)b * TT;
        int cur = p;
        dec[TT - 1] = (float)cur;
        for (int s = TT - 2; s >= 0; --s) {
            // bp_seq[s] = forward bp at step s+1, except row lastidx which
            // the reference overwrites with `pointer` for every tag.
            cur = (s == lastidx) ? p : (int)bp[s + 1][cur];
            dec[s] = (float)cur;
        }
    }
}

extern "C" void kernel_launch(void* const* d_in, const int* in_sizes, int n_in,
                              void* d_out, int out_size, void* d_ws, size_t ws_size,
                              hipStream_t stream) {
    const float* feats = (const float*)d_in[0];
    const int*   mask  = (const int*)d_in[1];
    const float* trans = (const float*)d_in[2];
    float* out = (float*)d_out;
    viterbi_pruned<<<NB, 256, 0, stream>>>(feats, mask, trans, out);
}

// Round 5
// 918.135 us; speedup vs baseline: 1.3563x; 1.3563x over previous
//
#include <hip/hip_runtime.h>

#define NB 128
#define TT 512
#define TAG 256
#define START (TAG - 2)
#define STOP (TAG - 1)
#define MARGIN 0.03125f   // >> max fp32 rounding slack (~1e-3 at |part|~2000)
#define NSLOT 8

// One block = one batch element = ONE wave (64 lanes). Lane owns tags
// j = s*64+lane, s=0..3. Zero barriers in the forward loop: wave-synchronous
// shfl/ballot coordination; same-wave LDS ops are processed in order, so the
// candidate-compaction write->read needs no barrier (no vmcnt(0) drain ->
// the 2-deep emit prefetch survives across steps).
// Exact pruning: rows with part[i] < pmax - (Tmax-Tmin) - MARGIN cannot win
// any column (value or first-occurrence argmax); surviving arithmetic is
// bit-identical to the reference: (emit + T) + part, strict > over ascending i
// (s-major, lane-minor enumeration = ascending i).
__global__ __launch_bounds__(64) void viterbi_wave(
    const float* __restrict__ feats,   // [NB][TT][TAG] f32
    const int*   __restrict__ mask,    // [NB][TT] i32
    const float* __restrict__ trans,   // [TAG][TAG] f32
    float* __restrict__ out)           // [NB] scores ++ [NB][TT] decode (as f32)
{
    __shared__ unsigned int bp2[TT][64];  // [t][lane]: 4 packed bp bytes, byte s = tag s*64+lane (128 KiB)
    __shared__ float pcand[TAG];          // compacted candidate part values
    __shared__ int   cand[TAG];           // compacted candidate indices (ascending i)
    __shared__ float dec_s[TT];

    const int b    = blockIdx.x;
    const int lane = threadIdx.x;

    const float* __restrict__ fb = feats + (size_t)b * TT * TAG;
    const int*   __restrict__ mb = mask  + (size_t)b * TT;

    // ---- length = sum(mask) ----
    int lm = 0;
    #pragma unroll
    for (int k = 0; k < 8; ++k) lm += mb[(k << 6) + lane];
    #pragma unroll
    for (int o = 32; o; o >>= 1) lm += __shfl_xor(lm, o);
    const int lastidx = (lm > 0) ? (lm - 1) : 0;

    // ---- global Tmax/Tmin (once; also warms L2 with trans) ----
    float tmx = -INFINITY, tmn = INFINITY;
    #pragma unroll 8
    for (int k = lane; k < TAG * TAG / 4; k += 64) {
        float4 v = ((const float4*)trans)[k];
        tmx = fmaxf(tmx, fmaxf(fmaxf(v.x, v.y), fmaxf(v.z, v.w)));
        tmn = fminf(tmn, fminf(fminf(v.x, v.y), fminf(v.z, v.w)));
    }
    #pragma unroll
    for (int o = 32; o; o >>= 1) {
        tmx = fmaxf(tmx, __shfl_xor(tmx, o));
        tmn = fminf(tmn, __shfl_xor(tmn, o));
    }
    const float Wwin = (tmx - tmn) + MARGIN;

    // ---- t = 0 ----
    float m[4], pl[4];
    #pragma unroll
    for (int s = 0; s < 4; ++s) {
        const int j = (s << 6) + lane;
        m[s]  = fb[j] + trans[START * TAG + j];
        pl[s] = m[s];                      // valid when lastidx == 0
    }

    // ---- emit/mask prefetch, 2 steps deep (covers ~900cyc cold latency) ----
    float eA[4], eB[4];
    #pragma unroll
    for (int s = 0; s < 4; ++s) eA[s] = fb[TAG + (s << 6) + lane];
    #pragma unroll
    for (int s = 0; s < 4; ++s) eB[s] = fb[2 * TAG + (s << 6) + lane];
    int mkA = mb[1];
    int mkB = mb[2];

    // ---- forward scan, ZERO barriers ----
    for (int t = 1; t < TT; ++t) {
        float e0[4];
        #pragma unroll
        for (int s = 0; s < 4; ++s) e0[s] = eA[s];
        const int mk = mkA;
        #pragma unroll
        for (int s = 0; s < 4; ++s) eA[s] = eB[s];
        mkA = mkB;
        const int tp = (t + 2 <= TT - 1) ? (t + 2) : (TT - 1);
        #pragma unroll
        for (int s = 0; s < 4; ++s) eB[s] = fb[(size_t)tp * TAG + (s << 6) + lane];
        mkB = mb[tp];

        // threshold from exact pmax of part
        float px = fmaxf(fmaxf(m[0], m[1]), fmaxf(m[2], m[3]));
        #pragma unroll
        for (int o = 32; o; o >>= 1) px = fmaxf(px, __shfl_xor(px, o));
        const float thr = px - Wwin;

        // compact candidates into LDS, ascending i (s-major, lane-minor)
        const unsigned long long bal0 = __ballot(m[0] >= thr);
        const unsigned long long bal1 = __ballot(m[1] >= thr);
        const unsigned long long bal2 = __ballot(m[2] >= thr);
        const unsigned long long bal3 = __ballot(m[3] >= thr);
        const int c0 = __popcll(bal0), c1 = __popcll(bal1),
                  c2 = __popcll(bal2), c3 = __popcll(bal3);
        const unsigned long long below = (1ull << lane) - 1ull;
        if (m[0] >= thr) { int r =                __popcll(bal0 & below); cand[r] = lane;       pcand[r] = m[0]; }
        if (m[1] >= thr) { int r = c0 +           __popcll(bal1 & below); cand[r] = 64  + lane; pcand[r] = m[1]; }
        if (m[2] >= thr) { int r = c0 + c1 +      __popcll(bal2 & below); cand[r] = 128 + lane; pcand[r] = m[2]; }
        if (m[3] >= thr) { int r = c0 + c1 + c2 + __popcll(bal3 & below); cand[r] = 192 + lane; pcand[r] = m[3]; }
        const int ncand = c0 + c1 + c2 + c3;     // >= 1 always (pmax row qualifies)

        float nm[4];
        int   bi[4];
        #pragma unroll
        for (int c = 0; c < 4; ++c) { nm[c] = -INFINITY; bi[c] = 0; }

        // 8 fixed slots: loads all issued together -> one exposed L2 latency.
        // (same-wave DS in-order: reads see this step's writes, no barrier)
        int   ics[NSLOT];
        float pvs[NSLOT];
        #pragma unroll
        for (int k = 0; k < NSLOT; ++k) {
            const int   icr = cand[k];           // uniform-addr LDS broadcast
            const float pvr = pcand[k];
            const bool  ok  = (k < ncand);
            ics[k] = ok ? icr : 0;               // clamp -> safe address
            pvs[k] = ok ? pvr : -INFINITY;       // can never win
        }
        float tv[NSLOT][4];
        #pragma unroll
        for (int k = 0; k < NSLOT; ++k) {
            #pragma unroll
            for (int c = 0; c < 4; ++c)
                tv[k][c] = trans[(size_t)ics[k] * TAG + (c << 6) + lane];
        }
        #pragma unroll
        for (int k = 0; k < NSLOT; ++k) {
            #pragma unroll
            for (int c = 0; c < 4; ++c) {
                const float cur = (e0[c] + tv[k][c]) + pvs[k];  // exact assoc
                if (cur > nm[c]) { nm[c] = cur; bi[c] = ics[k]; }
            }
        }
        // rare tail (ncand > NSLOT), still ascending i
        for (int k = NSLOT; k < ncand; ++k) {
            const int   icr = cand[k];
            const float pvr = pcand[k];
            #pragma unroll
            for (int c = 0; c < 4; ++c) {
                const float cur = (e0[c] + trans[(size_t)icr * TAG + (c << 6) + lane]) + pvr;
                if (cur > nm[c]) { nm[c] = cur; bi[c] = icr; }
            }
        }

        const unsigned int pack = (unsigned)bi[0] | ((unsigned)bi[1] << 8)
                                | ((unsigned)bi[2] << 16) | ((unsigned)bi[3] << 24);
        bp2[t][lane] = (mk > 0) ? pack : 0u;

        #pragma unroll
        for (int c = 0; c < 4; ++c) m[c] = nm[c];
        if (t == lastidx) {
            #pragma unroll
            for (int c = 0; c < 4; ++c) pl[c] = nm[c];
        }
    }

    // ---- stop transition + first-occurrence argmax ----
    float bv; int bj;
    {
        const float fv0 = pl[0] + trans[(size_t)lane         * TAG + STOP];
        const float fv1 = pl[1] + trans[(size_t)(64  + lane) * TAG + STOP];
        const float fv2 = pl[2] + trans[(size_t)(128 + lane) * TAG + STOP];
        const float fv3 = pl[3] + trans[(size_t)(192 + lane) * TAG + STOP];
        bv = fv0; bj = lane;
        if (fv1 > bv) { bv = fv1; bj = 64  + lane; }
        if (fv2 > bv) { bv = fv2; bj = 128 + lane; }
        if (fv3 > bv) { bv = fv3; bj = 192 + lane; }
        #pragma unroll
        for (int o = 32; o; o >>= 1) {
            const float ov = __shfl_xor(bv, o);
            const int   oj = __shfl_xor(bj, o);
            if (ov > bv || (ov == bv && oj < bj)) { bv = ov; bj = oj; }
        }
    }

    // ---- backtrack (lane 0; same-wave LDS in-order vs bp2 writes) ----
    if (lane == 0) {
        out[b] = bv;
        int cur = bj;
        dec_s[TT - 1] = (float)cur;
        const unsigned char* bpb = (const unsigned char*)bp2;
        for (int s = TT - 2; s >= 0; --s) {
            // bp row t=s+1; row lastidx is overwritten with `pointer` (ref)
            cur = (s == lastidx) ? bj
                                 : (int)bpb[((s + 1) << 8) + ((cur & 63) << 2) + (cur >> 6)];
            dec_s[s] = (float)cur;
        }
    }

    // ---- coalesced decode write ----
    float* dec = out + NB + (size_t)b * TT;
    #pragma unroll
    for (int k = 0; k < 8; ++k) dec[(k << 6) + lane] = dec_s[(k << 6) + lane];
}

extern "C" void kernel_launch(void* const* d_in, const int* in_sizes, int n_in,
                              void* d_out, int out_size, void* d_ws, size_t ws_size,
                              hipStream_t stream) {
    const float* feats = (const float*)d_in[0];
    const int*   mask  = (const int*)d_in[1];
    const float* trans = (const float*)d_in[2];
    float* out = (float*)d_out;
    viterbi_wave<<<NB, 64, 0, stream>>>(feats, mask, trans, out);
}